// Round 8
// baseline (23.381 us; speedup 1.0000x reference)
//
#include <hip/hip_runtime.h>
#include <hip/hip_bf16.h>
#include <hip/hip_fp16.h>
#include <math.h>

#define BB 32
#define NN 2048
#define BLK 256
#define NQG 8                    // query groups (of 32) per block
#define QB (NQG * 32)            // 256 queries per block
#define NCH (NN / QB)            // 8 query chunks
#define NBLK (2 * BB * NCH)      // 512 blocks = 2/CU
#define TPW 16                   // j-tiles (of 32 targets) per wave, in regs
#define MAGIC 0x5A17CAFEu

typedef _Float16 f16x8 __attribute__((ext_vector_type(8)));
typedef float f32x16 __attribute__((ext_vector_type(16)));

__device__ __forceinline__ unsigned pk2h(float a, float b) {
  union { _Float16 h[2]; unsigned u; } v;
  v.h[0] = (_Float16)a; v.h[1] = (_Float16)b;
  return v.u;
}

__device__ __forceinline__ f16x8 mkfrag(unsigned a, unsigned b) {
  union { unsigned u[4]; f16x8 f; } v;
  v.u[0] = a; v.u[1] = b; v.u[2] = 0u; v.u[3] = 0u;
  return v.f;
}

// 17-input min: 16 MFMA regs + running min; folds to v_min3 shapes (8 instrs).
__device__ __forceinline__ float min17(const f32x16& d, float mn) {
  float g0 = fminf(fminf(d[0], d[1]), d[2]);
  float g1 = fminf(fminf(d[3], d[4]), d[5]);
  float g2 = fminf(fminf(d[6], d[7]), d[8]);
  float g3 = fminf(fminf(d[9], d[10]), d[11]);
  float g4 = fminf(fminf(d[12], d[13]), d[14]);
  float h0 = fminf(fminf(g0, g1), g2);
  float h1 = fminf(fminf(g3, g4), d[15]);
  return fminf(fminf(h0, h1), mn);
}

// Single-node fused chamfer + BCE + grid reduction.
// Compute core identical to R7 (validated absmax 0.0). Tail: flag-based
// grid reduction -- block 0 consumes 512 partials after spinning on MAGIC
// flags (poison-robust: any garbage != MAGIC just means "not ready"),
// writes the scalar, resets flags to 0 for the next replay.
__global__ __launch_bounds__(BLK) void cham_onepass(
    const float* __restrict__ est, const float* __restrict__ gt,
    const float* __restrict__ lest, const float* __restrict__ lab,
    float* __restrict__ bsum, unsigned* __restrict__ done,
    float* __restrict__ out) {
  int id = blockIdx.x;
  int qc = id % NCH; id /= NCH;
  int b = id % BB;
  int dir = id / BB;

  const float* X = dir ? gt : est;   // queries
  const float* Y = dir ? est : gt;   // targets

  __shared__ unsigned long long sbq[QB];   // 2 KB packed B-frags
  __shared__ float partial[4][NQG][32];    // 4 KB per-wave mins

  int tid = threadIdx.x;
  int lane = tid & 63, w = tid >> 6, l31 = lane & 31;
  int qbase = qc * QB;

  // stage this block's 256 queries (thread tid <-> query qbase+tid)
  const float* xq = X + ((size_t)b * NN + qbase + tid) * 3;
  float x0 = xq[0], x1 = xq[1], x2 = xq[2];
  {
    union { unsigned u[2]; unsigned long long ull; } pb;
    pb.u[0] = pk2h(-x0, -x1);
    pb.u[1] = pk2h(-x2, 1.0f);
    sbq[tid] = pb.ull;
  }

  // load A-frags into registers (once, L2-hot: 64 blocks share each (dir,b))
  f16x8 A[TPW];
#pragma unroll
  for (int k = 0; k < TPW; ++k) {
    int j = (w + 4 * k) * 32 + l31;
    const float* yp = Y + ((size_t)b * NN + j) * 3;
    float y0 = yp[0], y1 = yp[1], y2 = yp[2];
    float h = 0.5f * (y0 * y0 + y1 * y1 + y2 * y2);
    A[k] = mkfrag(pk2h(y0, y1), pk2h(y2, h));
  }
  __syncthreads();

  const f32x16 zz = {0.f, 0.f, 0.f, 0.f, 0.f, 0.f, 0.f, 0.f,
                     0.f, 0.f, 0.f, 0.f, 0.f, 0.f, 0.f, 0.f};

#pragma unroll 2
  for (int n = 0; n < NQG; ++n) {
    union { unsigned long long ull; unsigned u[2]; } qb;
    qb.ull = sbq[n * 32 + l31];
    f16x8 bf = mkfrag(qb.u[0], qb.u[1]);
    float m0 = 3.4e38f, m1 = 3.4e38f, m2 = 3.4e38f, m3 = 3.4e38f;
#pragma unroll
    for (int t = 0; t < TPW; t += 4) {
      f32x16 d0 = __builtin_amdgcn_mfma_f32_32x32x16_f16(A[t + 0], bf, zz, 0, 0, 0);
      f32x16 d1 = __builtin_amdgcn_mfma_f32_32x32x16_f16(A[t + 1], bf, zz, 0, 0, 0);
      f32x16 d2 = __builtin_amdgcn_mfma_f32_32x32x16_f16(A[t + 2], bf, zz, 0, 0, 0);
      f32x16 d3 = __builtin_amdgcn_mfma_f32_32x32x16_f16(A[t + 3], bf, zz, 0, 0, 0);
      m0 = min17(d0, m0);
      m1 = min17(d1, m1);
      m2 = min17(d2, m2);
      m3 = min17(d3, m3);
    }
    float m = fminf(fminf(m0, m1), fminf(m2, m3));
    m = fminf(m, __shfl_xor(m, 32, 64));  // merge row halves
    if (lane < 32) partial[w][n][l31] = m;
  }
  __syncthreads();

  // epilogue: thread tid <-> query qbase+tid; n = tid>>5, col = tid&31
  int n = tid >> 5, col = tid & 31;
  float m = fminf(fminf(partial[0][n][col], partial[1][n][col]),
                  fminf(partial[2][n][col], partial[3][n][col]));
  float x2n = fmaf(x0, x0, fmaf(x1, x1, x2 * x2));
  float val = fmaxf(x2n + m, 0.0f);
  if (!dir) {  // fuse BCE for (b, qbase+tid)
    float z = lest[(size_t)b * NN + qbase + tid];
    float t = lab[(size_t)b * NN + qbase + tid];
    val += fmaxf(z, 0.0f) - z * t + log1pf(expf(-fabsf(z)));
  }

  for (int off = 32; off > 0; off >>= 1) val += __shfl_down(val, off);
  __shared__ float wsum[BLK / 64];
  if (lane == 0) wsum[w] = val;
  __syncthreads();
  if (tid == 0) {
    float s = wsum[0] + wsum[1] + wsum[2] + wsum[3];
    atomicExch(&bsum[blockIdx.x], s);   // device-scope, cross-XCD coherent
    __threadfence();
    atomicExch(&done[blockIdx.x], MAGIC);
  }

  // ---- consumer: block 0 gathers all partials, writes the scalar ----
  if (blockIdx.x == 0) {
    float acc = 0.0f;
#pragma unroll
    for (int k = 0; k < NBLK / BLK; ++k) {
      int s = tid + k * BLK;
      while (atomicAdd(&done[s], 0u) != MAGIC) {
        __builtin_amdgcn_s_sleep(2);
      }
      acc += atomicAdd(&bsum[s], 0.0f);  // coherent read
    }
    for (int off = 32; off > 0; off >>= 1) acc += __shfl_down(acc, off);
    __shared__ float csum[BLK / 64];
    if (lane == 0) csum[w] = acc;
    __syncthreads();
    if (tid == 0)
      out[0] = (csum[0] + csum[1] + csum[2] + csum[3]) *
               (1.0f / ((float)BB * (float)NN));
    // reset flags for the next replay (after consumption)
#pragma unroll
    for (int k = 0; k < NBLK / BLK; ++k)
      atomicExch(&done[tid + k * BLK], 0u);
  }
}

// Fallback (proven-correct R1 kernel) if ws is too small.
__global__ __launch_bounds__(BLK) void chamfer_bce_kernel(
    const float* __restrict__ est, const float* __restrict__ gt,
    const float* __restrict__ lest, const float* __restrict__ lab,
    float* __restrict__ out) {
  int bid = blockIdx.x;
  int dir = (bid >= BB * (NN / BLK)) ? 1 : 0;
  int id = dir ? (bid - BB * (NN / BLK)) : bid;
  int b = id / (NN / BLK);
  int tile = id % (NN / BLK);
  const float* X = dir ? gt : est;
  const float* Y = dir ? est : gt;
  __shared__ float4 sy[NN];
  const float* yb = Y + (size_t)b * NN * 3;
  for (int j = threadIdx.x; j < NN; j += BLK)
    sy[j] = make_float4(yb[3 * j], yb[3 * j + 1], yb[3 * j + 2], 0.0f);
  __syncthreads();
  int i = tile * BLK + threadIdx.x;
  const float* xb = X + (size_t)b * NN * 3 + (size_t)3 * i;
  float ex = xb[0], ey = xb[1], ez = xb[2];
  float m0 = 3.4e38f, m1 = 3.4e38f, m2 = 3.4e38f, m3 = 3.4e38f;
#pragma unroll 4
  for (int j = 0; j < NN; j += 4) {
    float4 p0 = sy[j], p1 = sy[j + 1], p2 = sy[j + 2], p3 = sy[j + 3];
    { float dx = ex - p0.x, dy = ey - p0.y, dz = ez - p0.z;
      m0 = fminf(m0, fmaf(dx, dx, fmaf(dy, dy, dz * dz))); }
    { float dx = ex - p1.x, dy = ey - p1.y, dz = ez - p1.z;
      m1 = fminf(m1, fmaf(dx, dx, fmaf(dy, dy, dz * dz))); }
    { float dx = ex - p2.x, dy = ey - p2.y, dz = ez - p2.z;
      m2 = fminf(m2, fmaf(dx, dx, fmaf(dy, dy, dz * dz))); }
    { float dx = ex - p3.x, dy = ey - p3.y, dz = ez - p3.z;
      m3 = fminf(m3, fmaf(dx, dx, fmaf(dy, dy, dz * dz))); }
  }
  float val = fminf(fminf(m0, m1), fminf(m2, m3));
  if (!dir) {
    float z = lest[(size_t)b * NN + i];
    float t = lab[(size_t)b * NN + i];
    val += fmaxf(z, 0.0f) - z * t + log1pf(expf(-fabsf(z)));
  }
  for (int off = 32; off > 0; off >>= 1) val += __shfl_down(val, off);
  __shared__ float wsum[BLK / 64];
  int lane = threadIdx.x & 63;
  int wid = threadIdx.x >> 6;
  if (lane == 0) wsum[wid] = val;
  __syncthreads();
  if (threadIdx.x == 0) {
    float s = 0.0f;
#pragma unroll
    for (int w = 0; w < BLK / 64; ++w) s += wsum[w];
    atomicAdd(out, s * (1.0f / ((float)BB * (float)NN)));
  }
}

extern "C" void kernel_launch(void* const* d_in, const int* in_sizes, int n_in,
                              void* d_out, int out_size, void* d_ws, size_t ws_size,
                              hipStream_t stream) {
  const float* est = (const float*)d_in[0];
  const float* gt = (const float*)d_in[1];
  const float* lest = (const float*)d_in[2];
  const float* lab = (const float*)d_in[3];
  float* out = (float*)d_out;

  const size_t need = (size_t)NBLK * (sizeof(float) + sizeof(unsigned));
  if (ws_size >= need) {
    float* bsum = (float*)d_ws;
    unsigned* done = (unsigned*)((char*)d_ws + NBLK * sizeof(float));
    cham_onepass<<<dim3(NBLK), dim3(BLK), 0, stream>>>(est, gt, lest, lab,
                                                       bsum, done, out);
  } else {
    hipMemsetAsync(out, 0, sizeof(float), stream);
    chamfer_bce_kernel<<<dim3(2 * BB * (NN / BLK)), dim3(BLK), 0, stream>>>(
        est, gt, lest, lab, out);
  }
}

// Round 9
// 21.549 us; speedup vs baseline: 1.0850x; 1.0850x over previous
//
#include <hip/hip_runtime.h>
#include <hip/hip_bf16.h>
#include <hip/hip_fp16.h>
#include <math.h>

#define BB 32
#define NN 2048
#define BLK 256
#define NQG 4                    // query groups (of 32) per block
#define QB (NQG * 32)            // 128 queries per block
#define NCH (NN / QB)            // 16 query chunks
#define NBLK (2 * BB * NCH)      // 1024 blocks = 4/CU
#define TPW 16                   // j-tiles (of 32 targets) per wave, in regs

typedef _Float16 f16x8 __attribute__((ext_vector_type(8)));
typedef float f32x16 __attribute__((ext_vector_type(16)));

__device__ __forceinline__ unsigned pk2h(float a, float b) {
  union { _Float16 h[2]; unsigned u; } v;
  v.h[0] = (_Float16)a; v.h[1] = (_Float16)b;
  return v.u;
}

__device__ __forceinline__ f16x8 mkfrag(unsigned a, unsigned b) {
  union { unsigned u[4]; f16x8 f; } v;
  v.u[0] = a; v.u[1] = b; v.u[2] = 0u; v.u[3] = 0u;
  return v.f;
}

// Single v_min3_f32 (no NaN inputs in this problem; fminf trees don't fold).
__device__ __forceinline__ float min3f(float a, float b, float c) {
  float r;
  asm("v_min3_f32 %0, %1, %2, %3" : "=v"(r) : "v"(a), "v"(b), "v"(c));
  return r;
}

// 17-input min in exactly 8 v_min3_f32.
__device__ __forceinline__ float min17(const f32x16& d, float mn) {
  float t0 = min3f(d[0], d[1], d[2]);
  float t1 = min3f(d[3], d[4], d[5]);
  float t2 = min3f(d[6], d[7], d[8]);
  float t3 = min3f(d[9], d[10], d[11]);
  float t4 = min3f(d[12], d[13], d[14]);
  float u0 = min3f(t0, t1, t2);
  float u1 = min3f(t3, t4, d[15]);
  return min3f(u0, u1, mn);
}

// Register-resident chamfer (R7 core, min3 reduction, grid 1024).
// Block (dir, b, qc): 128 queries vs all 2048 targets. Wave w holds 16
// A-frags (tiles w, w+4k) in VGPRs (y0,y1,y2,|y|^2/2 packed f16, both
// k-halves identical -> D = |y|^2 - 2 x.y; bit-exact validated R4-R8).
// Inner: 4 query groups; one 8B LDS read -> B-frag (-x,1) -> 16 MFMAs ->
// 8 min3 each. Per-wave mins to LDS, cross-wave fold, + x^2, + BCE
// (dir==0), block sum -> bsum.
__global__ __launch_bounds__(BLK) void cham_fused(
    const float* __restrict__ est, const float* __restrict__ gt,
    const float* __restrict__ lest, const float* __restrict__ lab,
    float* __restrict__ bsum) {
  int id = blockIdx.x;
  int qc = id % NCH; id /= NCH;
  int b = id % BB;
  int dir = id / BB;

  const float* X = dir ? gt : est;   // queries
  const float* Y = dir ? est : gt;   // targets

  __shared__ unsigned long long sbq[QB];   // 1 KB packed B-frags
  __shared__ float partial[4][NQG][32];    // 2 KB per-wave mins

  int tid = threadIdx.x;
  int lane = tid & 63, w = tid >> 6, l31 = lane & 31;
  int qbase = qc * QB;

  // stage this block's 128 queries (thread tid <-> query qbase+tid, tid<QB)
  float x0 = 0.0f, x1 = 0.0f, x2 = 0.0f;
  if (tid < QB) {
    const float* xq = X + ((size_t)b * NN + qbase + tid) * 3;
    x0 = xq[0]; x1 = xq[1]; x2 = xq[2];
    union { unsigned u[2]; unsigned long long ull; } pb;
    pb.u[0] = pk2h(-x0, -x1);
    pb.u[1] = pk2h(-x2, 1.0f);
    sbq[tid] = pb.ull;
  }

  // load A-frags into registers (once; L2-hot: 32 blocks share each (dir,b))
  f16x8 A[TPW];
#pragma unroll
  for (int k = 0; k < TPW; ++k) {
    int j = (w + 4 * k) * 32 + l31;
    const float* yp = Y + ((size_t)b * NN + j) * 3;
    float y0 = yp[0], y1 = yp[1], y2 = yp[2];
    float h = 0.5f * (y0 * y0 + y1 * y1 + y2 * y2);
    A[k] = mkfrag(pk2h(y0, y1), pk2h(y2, h));
  }
  __syncthreads();

  const f32x16 zz = {0.f, 0.f, 0.f, 0.f, 0.f, 0.f, 0.f, 0.f,
                     0.f, 0.f, 0.f, 0.f, 0.f, 0.f, 0.f, 0.f};

#pragma unroll 2
  for (int n = 0; n < NQG; ++n) {
    union { unsigned long long ull; unsigned u[2]; } qb;
    qb.ull = sbq[n * 32 + l31];
    f16x8 bf = mkfrag(qb.u[0], qb.u[1]);
    // 4 independent min chains over 16 MFMAs
    float m0 = 3.4e38f, m1 = 3.4e38f, m2 = 3.4e38f, m3 = 3.4e38f;
#pragma unroll
    for (int t = 0; t < TPW; t += 4) {
      f32x16 d0 = __builtin_amdgcn_mfma_f32_32x32x16_f16(A[t + 0], bf, zz, 0, 0, 0);
      f32x16 d1 = __builtin_amdgcn_mfma_f32_32x32x16_f16(A[t + 1], bf, zz, 0, 0, 0);
      f32x16 d2 = __builtin_amdgcn_mfma_f32_32x32x16_f16(A[t + 2], bf, zz, 0, 0, 0);
      f32x16 d3 = __builtin_amdgcn_mfma_f32_32x32x16_f16(A[t + 3], bf, zz, 0, 0, 0);
      m0 = min17(d0, m0);
      m1 = min17(d1, m1);
      m2 = min17(d2, m2);
      m3 = min17(d3, m3);
    }
    float m = min3f(fminf(m0, m1), m2, m3);
    m = fminf(m, __shfl_xor(m, 32, 64));  // merge row halves
    if (lane < 32) partial[w][n][l31] = m;
  }
  __syncthreads();

  // epilogue: thread tid <-> query qbase+tid (tid < QB)
  float val = 0.0f;
  if (tid < QB) {
    int n = tid >> 5, col = tid & 31;
    float m = fminf(fminf(partial[0][n][col], partial[1][n][col]),
                    fminf(partial[2][n][col], partial[3][n][col]));
    float x2n = fmaf(x0, x0, fmaf(x1, x1, x2 * x2));
    val = fmaxf(x2n + m, 0.0f);
    if (!dir) {  // fuse BCE for (b, qbase+tid)
      float z = lest[(size_t)b * NN + qbase + tid];
      float t = lab[(size_t)b * NN + qbase + tid];
      val += fmaxf(z, 0.0f) - z * t + log1pf(expf(-fabsf(z)));
    }
  }

  for (int off = 32; off > 0; off >>= 1) val += __shfl_down(val, off);
  __shared__ float wsum[BLK / 64];
  if (lane == 0) wsum[w] = val;
  __syncthreads();
  if (tid == 0)
    bsum[blockIdx.x] = wsum[0] + wsum[1] + wsum[2] + wsum[3];
}

// Final: sum 1024 block partials, scale, store scalar. Deterministic.
__global__ __launch_bounds__(BLK) void sum_kernel(
    const float* __restrict__ bsum, float* __restrict__ out) {
  float val = 0.0f;
#pragma unroll
  for (int k = 0; k < NBLK / BLK; ++k) val += bsum[threadIdx.x + k * BLK];
  for (int off = 32; off > 0; off >>= 1) val += __shfl_down(val, off);
  __shared__ float wsum[BLK / 64];
  int lane = threadIdx.x & 63;
  int wid = threadIdx.x >> 6;
  if (lane == 0) wsum[wid] = val;
  __syncthreads();
  if (threadIdx.x == 0) {
    float s = 0.0f;
#pragma unroll
    for (int wv = 0; wv < BLK / 64; ++wv) s += wsum[wv];
    out[0] = s * (1.0f / ((float)BB * (float)NN));
  }
}

// Fallback (proven-correct R1 kernel) if ws is too small.
__global__ __launch_bounds__(BLK) void chamfer_bce_kernel(
    const float* __restrict__ est, const float* __restrict__ gt,
    const float* __restrict__ lest, const float* __restrict__ lab,
    float* __restrict__ out) {
  int bid = blockIdx.x;
  int dir = (bid >= BB * (NN / BLK)) ? 1 : 0;
  int id = dir ? (bid - BB * (NN / BLK)) : bid;
  int b = id / (NN / BLK);
  int tile = id % (NN / BLK);
  const float* X = dir ? gt : est;
  const float* Y = dir ? est : gt;
  __shared__ float4 sy[NN];
  const float* yb = Y + (size_t)b * NN * 3;
  for (int j = threadIdx.x; j < NN; j += BLK)
    sy[j] = make_float4(yb[3 * j], yb[3 * j + 1], yb[3 * j + 2], 0.0f);
  __syncthreads();
  int i = tile * BLK + threadIdx.x;
  const float* xb = X + (size_t)b * NN * 3 + (size_t)3 * i;
  float ex = xb[0], ey = xb[1], ez = xb[2];
  float m0 = 3.4e38f, m1 = 3.4e38f, m2 = 3.4e38f, m3 = 3.4e38f;
#pragma unroll 4
  for (int j = 0; j < NN; j += 4) {
    float4 p0 = sy[j], p1 = sy[j + 1], p2 = sy[j + 2], p3 = sy[j + 3];
    { float dx = ex - p0.x, dy = ey - p0.y, dz = ez - p0.z;
      m0 = fminf(m0, fmaf(dx, dx, fmaf(dy, dy, dz * dz))); }
    { float dx = ex - p1.x, dy = ey - p1.y, dz = ez - p1.z;
      m1 = fminf(m1, fmaf(dx, dx, fmaf(dy, dy, dz * dz))); }
    { float dx = ex - p2.x, dy = ey - p2.y, dz = ez - p2.z;
      m2 = fminf(m2, fmaf(dx, dx, fmaf(dy, dy, dz * dz))); }
    { float dx = ex - p3.x, dy = ey - p3.y, dz = ez - p3.z;
      m3 = fminf(m3, fmaf(dx, dx, fmaf(dy, dy, dz * dz))); }
  }
  float val = fminf(fminf(m0, m1), fminf(m2, m3));
  if (!dir) {
    float z = lest[(size_t)b * NN + i];
    float t = lab[(size_t)b * NN + i];
    val += fmaxf(z, 0.0f) - z * t + log1pf(expf(-fabsf(z)));
  }
  for (int off = 32; off > 0; off >>= 1) val += __shfl_down(val, off);
  __shared__ float wsum[BLK / 64];
  int lane = threadIdx.x & 63;
  int wid = threadIdx.x >> 6;
  if (lane == 0) wsum[wid] = val;
  __syncthreads();
  if (threadIdx.x == 0) {
    float s = 0.0f;
#pragma unroll
    for (int w = 0; w < BLK / 64; ++w) s += wsum[w];
    atomicAdd(out, s * (1.0f / ((float)BB * (float)NN)));
  }
}

extern "C" void kernel_launch(void* const* d_in, const int* in_sizes, int n_in,
                              void* d_out, int out_size, void* d_ws, size_t ws_size,
                              hipStream_t stream) {
  const float* est = (const float*)d_in[0];
  const float* gt = (const float*)d_in[1];
  const float* lest = (const float*)d_in[2];
  const float* lab = (const float*)d_in[3];
  float* out = (float*)d_out;

  const size_t need = (size_t)NBLK * sizeof(float);  // 4 KB
  if (ws_size >= need) {
    float* bsum = (float*)d_ws;
    cham_fused<<<dim3(NBLK), dim3(BLK), 0, stream>>>(est, gt, lest, lab, bsum);
    sum_kernel<<<dim3(1), dim3(BLK), 0, stream>>>(bsum, out);
  } else {
    hipMemsetAsync(out, 0, sizeof(float), stream);
    chamfer_bce_kernel<<<dim3(2 * BB * (NN / BLK)), dim3(BLK), 0, stream>>>(
        est, gt, lest, lab, out);
  }
}

// Round 10
// 16.613 us; speedup vs baseline: 1.4074x; 1.2971x over previous
//
#include <hip/hip_runtime.h>
#include <hip/hip_bf16.h>
#include <hip/hip_fp16.h>
#include <math.h>

#define BB 32
#define NN 2048
#define BLK 256
#define NQG 4                    // query groups (of 32) per block
#define QB (NQG * 32)            // 128 queries per block
#define NCH (NN / QB)            // 16 query chunks
#define NBLK (2 * BB * NCH)      // 1024 blocks = 4/CU
#define TPW 8                    // j-tiles held in regs at once (32 VGPRs)
#define NROUND 2                 // 2 rounds x 8 tiles = 16 tiles per wave

typedef _Float16 f16x8 __attribute__((ext_vector_type(8)));
typedef float f32x16 __attribute__((ext_vector_type(16)));

__device__ __forceinline__ unsigned pk2h(float a, float b) {
  union { _Float16 h[2]; unsigned u; } v;
  v.h[0] = (_Float16)a; v.h[1] = (_Float16)b;
  return v.u;
}

__device__ __forceinline__ f16x8 mkfrag(unsigned a, unsigned b) {
  union { unsigned u[4]; f16x8 f; } v;
  v.u[0] = a; v.u[1] = b; v.u[2] = 0u; v.u[3] = 0u;
  return v.f;
}

__device__ __forceinline__ float min3f(float a, float b, float c) {
  float r;
  asm("v_min3_f32 %0, %1, %2, %3" : "=v"(r) : "v"(a), "v"(b), "v"(c));
  return r;
}

// 17-input min in 8 v_min3_f32.
__device__ __forceinline__ float min17(const f32x16& d, float mn) {
  float t0 = min3f(d[0], d[1], d[2]);
  float t1 = min3f(d[3], d[4], d[5]);
  float t2 = min3f(d[6], d[7], d[8]);
  float t3 = min3f(d[9], d[10], d[11]);
  float t4 = min3f(d[12], d[13], d[14]);
  float u0 = min3f(t0, t1, t2);
  float u1 = min3f(t3, t4, d[15]);
  return min3f(u0, u1, mn);
}

// Register-resident chamfer, VGPR-slimmed for 4 waves/SIMD occupancy.
// Block (dir, b, qc): 128 queries vs all 2048 targets. Wave w holds 8
// A-frags at a time (tiles w+4*(8r+k), 2 rounds), 2 MFMA dst chains.
// Compute identity (D = |y|^2 - 2 x.y via duplicated k-halves) unchanged,
// bit-exact validated R4-R9.
__global__ __launch_bounds__(BLK, 4) void cham_fused(
    const float* __restrict__ est, const float* __restrict__ gt,
    const float* __restrict__ lest, const float* __restrict__ lab,
    float* __restrict__ bsum) {
  int id = blockIdx.x;
  int qc = id % NCH; id /= NCH;
  int b = id % BB;
  int dir = id / BB;

  const float* X = dir ? gt : est;   // queries
  const float* Y = dir ? est : gt;   // targets

  __shared__ unsigned long long sbq[QB];   // 1 KB packed B-frags
  __shared__ float partial[4][NQG][32];    // 2 KB per-wave mins

  int tid = threadIdx.x;
  int lane = tid & 63, w = tid >> 6, l31 = lane & 31;
  int qbase = qc * QB;

  // stage this block's 128 queries (thread tid <-> query qbase+tid, tid<QB)
  float x0 = 0.0f, x1 = 0.0f, x2 = 0.0f;
  if (tid < QB) {
    const float* xq = X + ((size_t)b * NN + qbase + tid) * 3;
    x0 = xq[0]; x1 = xq[1]; x2 = xq[2];
    union { unsigned u[2]; unsigned long long ull; } pb;
    pb.u[0] = pk2h(-x0, -x1);
    pb.u[1] = pk2h(-x2, 1.0f);
    sbq[tid] = pb.ull;
  }
  __syncthreads();

  const f32x16 zz = {0.f, 0.f, 0.f, 0.f, 0.f, 0.f, 0.f, 0.f,
                     0.f, 0.f, 0.f, 0.f, 0.f, 0.f, 0.f, 0.f};

  for (int r = 0; r < NROUND; ++r) {
    // load this round's 8 A-frags (L2-hot; 32 VGPRs)
    f16x8 A[TPW];
#pragma unroll
    for (int k = 0; k < TPW; ++k) {
      int j = (w + 4 * (r * TPW + k)) * 32 + l31;
      const float* yp = Y + ((size_t)b * NN + j) * 3;
      float y0 = yp[0], y1 = yp[1], y2 = yp[2];
      float h = 0.5f * (y0 * y0 + y1 * y1 + y2 * y2);
      A[k] = mkfrag(pk2h(y0, y1), pk2h(y2, h));
    }

#pragma unroll
    for (int n = 0; n < NQG; ++n) {
      union { unsigned long long ull; unsigned u[2]; } qb;
      qb.ull = sbq[n * 32 + l31];
      f16x8 bf = mkfrag(qb.u[0], qb.u[1]);
      float m0 = 3.4e38f, m1 = 3.4e38f;
      __builtin_amdgcn_s_setprio(1);
#pragma unroll
      for (int t = 0; t < TPW; t += 2) {
        f32x16 d0 = __builtin_amdgcn_mfma_f32_32x32x16_f16(A[t + 0], bf, zz, 0, 0, 0);
        f32x16 d1 = __builtin_amdgcn_mfma_f32_32x32x16_f16(A[t + 1], bf, zz, 0, 0, 0);
        m0 = min17(d0, m0);
        m1 = min17(d1, m1);
      }
      __builtin_amdgcn_s_setprio(0);
      float m = fminf(m0, m1);
      m = fminf(m, __shfl_xor(m, 32, 64));  // merge row halves
      if (lane < 32) {
        if (r == 0)
          partial[w][n][l31] = m;
        else
          partial[w][n][l31] = fminf(partial[w][n][l31], m);
      }
    }
  }
  __syncthreads();

  // epilogue: thread tid <-> query qbase+tid (tid < QB)
  float val = 0.0f;
  if (tid < QB) {
    int n = tid >> 5, col = tid & 31;
    float m = fminf(fminf(partial[0][n][col], partial[1][n][col]),
                    fminf(partial[2][n][col], partial[3][n][col]));
    float x2n = fmaf(x0, x0, fmaf(x1, x1, x2 * x2));
    val = fmaxf(x2n + m, 0.0f);
    if (!dir) {  // fuse BCE for (b, qbase+tid)
      float z = lest[(size_t)b * NN + qbase + tid];
      float t = lab[(size_t)b * NN + qbase + tid];
      val += fmaxf(z, 0.0f) - z * t + log1pf(expf(-fabsf(z)));
    }
  }

  for (int off = 32; off > 0; off >>= 1) val += __shfl_down(val, off);
  __shared__ float wsum[BLK / 64];
  if (lane == 0) wsum[w] = val;
  __syncthreads();
  if (tid == 0)
    bsum[blockIdx.x] = wsum[0] + wsum[1] + wsum[2] + wsum[3];
}

// Final: sum 1024 block partials, scale, store scalar. Deterministic.
__global__ __launch_bounds__(BLK) void sum_kernel(
    const float* __restrict__ bsum, float* __restrict__ out) {
  float val = 0.0f;
#pragma unroll
  for (int k = 0; k < NBLK / BLK; ++k) val += bsum[threadIdx.x + k * BLK];
  for (int off = 32; off > 0; off >>= 1) val += __shfl_down(val, off);
  __shared__ float wsum[BLK / 64];
  int lane = threadIdx.x & 63;
  int wid = threadIdx.x >> 6;
  if (lane == 0) wsum[wid] = val;
  __syncthreads();
  if (threadIdx.x == 0) {
    float s = 0.0f;
#pragma unroll
    for (int wv = 0; wv < BLK / 64; ++wv) s += wsum[wv];
    out[0] = s * (1.0f / ((float)BB * (float)NN));
  }
}

// Fallback (proven-correct R1 kernel) if ws is too small.
__global__ __launch_bounds__(BLK) void chamfer_bce_kernel(
    const float* __restrict__ est, const float* __restrict__ gt,
    const float* __restrict__ lest, const float* __restrict__ lab,
    float* __restrict__ out) {
  int bid = blockIdx.x;
  int dir = (bid >= BB * (NN / BLK)) ? 1 : 0;
  int id = dir ? (bid - BB * (NN / BLK)) : bid;
  int b = id / (NN / BLK);
  int tile = id % (NN / BLK);
  const float* X = dir ? gt : est;
  const float* Y = dir ? est : gt;
  __shared__ float4 sy[NN];
  const float* yb = Y + (size_t)b * NN * 3;
  for (int j = threadIdx.x; j < NN; j += BLK)
    sy[j] = make_float4(yb[3 * j], yb[3 * j + 1], yb[3 * j + 2], 0.0f);
  __syncthreads();
  int i = tile * BLK + threadIdx.x;
  const float* xb = X + (size_t)b * NN * 3 + (size_t)3 * i;
  float ex = xb[0], ey = xb[1], ez = xb[2];
  float m0 = 3.4e38f, m1 = 3.4e38f, m2 = 3.4e38f, m3 = 3.4e38f;
#pragma unroll 4
  for (int j = 0; j < NN; j += 4) {
    float4 p0 = sy[j], p1 = sy[j + 1], p2 = sy[j + 2], p3 = sy[j + 3];
    { float dx = ex - p0.x, dy = ey - p0.y, dz = ez - p0.z;
      m0 = fminf(m0, fmaf(dx, dx, fmaf(dy, dy, dz * dz))); }
    { float dx = ex - p1.x, dy = ey - p1.y, dz = ez - p1.z;
      m1 = fminf(m1, fmaf(dx, dx, fmaf(dy, dy, dz * dz))); }
    { float dx = ex - p2.x, dy = ey - p2.y, dz = ez - p2.z;
      m2 = fminf(m2, fmaf(dx, dx, fmaf(dy, dy, dz * dz))); }
    { float dx = ex - p3.x, dy = ey - p3.y, dz = ez - p3.z;
      m3 = fminf(m3, fmaf(dx, dx, fmaf(dy, dy, dz * dz))); }
  }
  float val = fminf(fminf(m0, m1), fminf(m2, m3));
  if (!dir) {
    float z = lest[(size_t)b * NN + i];
    float t = lab[(size_t)b * NN + i];
    val += fmaxf(z, 0.0f) - z * t + log1pf(expf(-fabsf(z)));
  }
  for (int off = 32; off > 0; off >>= 1) val += __shfl_down(val, off);
  __shared__ float wsum[BLK / 64];
  int lane = threadIdx.x & 63;
  int wid = threadIdx.x >> 6;
  if (lane == 0) wsum[wid] = val;
  __syncthreads();
  if (threadIdx.x == 0) {
    float s = 0.0f;
#pragma unroll
    for (int w = 0; w < BLK / 64; ++w) s += wsum[w];
    atomicAdd(out, s * (1.0f / ((float)BB * (float)NN)));
  }
}

extern "C" void kernel_launch(void* const* d_in, const int* in_sizes, int n_in,
                              void* d_out, int out_size, void* d_ws, size_t ws_size,
                              hipStream_t stream) {
  const float* est = (const float*)d_in[0];
  const float* gt = (const float*)d_in[1];
  const float* lest = (const float*)d_in[2];
  const float* lab = (const float*)d_in[3];
  float* out = (float*)d_out;

  const size_t need = (size_t)NBLK * sizeof(float);  // 4 KB
  if (ws_size >= need) {
    float* bsum = (float*)d_ws;
    cham_fused<<<dim3(NBLK), dim3(BLK), 0, stream>>>(est, gt, lest, lab, bsum);
    sum_kernel<<<dim3(1), dim3(BLK), 0, stream>>>(bsum, out);
  } else {
    hipMemsetAsync(out, 0, sizeof(float), stream);
    chamfer_bce_kernel<<<dim3(2 * BB * (NN / BLK)), dim3(BLK), 0, stream>>>(
        est, gt, lest, lab, out);
  }
}